// Round 4
// baseline (440.058 us; speedup 1.0000x reference)
//
#include <hip/hip_runtime.h>

#define HW 56
#define NPIX 3136          // 56*56
#define CIN 256
#define OUTC 256

typedef unsigned short ushort_t;
typedef unsigned int uint_t;

__device__ __forceinline__ float b2f(ushort_t u){ return __uint_as_float(((uint_t)u)<<16); }
__device__ __forceinline__ ushort_t f2b(float f){
  uint_t u = __float_as_uint(f);
  u += 0x7fffu + ((u>>16)&1u);
  return (ushort_t)(u>>16);
}
__device__ __forceinline__ int refl(int v){ v = v<0 ? -v : v; return v>=HW ? 2*HW-2-v : v; }

// ---- workspace layout (float element offsets unless noted) ----
#define WT_OFF   0          // Wt[256][288] fp32 (transposed proj weights, rows=cin)
#define BF_OFF   73728      // bias[288] (pad to 320)
#define CW1_OFF  74048      // cw1[16][16]
#define CW2_OFF  74304      // cw2[32][16]
#define CW2B_OFF 74816      // cw2b[32] (pad 64)
#define BNC_OFF  74880      // bn1s[16] bn1b[16] bn2s[16] bn2b[16]
#define P2T_OFF  74944      // P2t[57][256] = 14592, P2t[i][g*8+o] = p2[g][o][i]
#define X1_OFF   89600      // x1f[4][16][3136]
#define X2_OFF   290304     // x2f[4][16][3136]
#define X3_BYTE_OFF 1964032 // x3b[4][3136][256] bf16 (6,422,528 B) -> total ws = 8,386,560 B

// ===================== K0: weight prep (fp32 inputs) =====================
__global__ void k0_prep(const float* __restrict__ w1, const float* __restrict__ b1,
                        const float* __restrict__ w2, const float* __restrict__ b2,
                        const float* __restrict__ w3, const float* __restrict__ b3,
                        const float* __restrict__ g1, const float* __restrict__ be1,
                        const float* __restrict__ m1, const float* __restrict__ v1,
                        const float* __restrict__ cw1,
                        const float* __restrict__ g2, const float* __restrict__ be2,
                        const float* __restrict__ m2, const float* __restrict__ v2,
                        const float* __restrict__ cw2, const float* __restrict__ cw2b,
                        const float* __restrict__ p2,
                        float* __restrict__ ws)
{
  int idx = blockIdx.x*256 + threadIdx.x;
  if (idx < 73728){                       // Wt[c][r] = W[r][c]
    int c = idx / 288, r = idx - c*288;
    float v;
    if (r < 16)      v = w1[r*256 + c];
    else if (r < 32) v = w2[(r-16)*256 + c];
    else             v = w3[(r-32)*256 + c];
    ws[WT_OFF + idx] = v;
    return;
  }
  int j = idx - 73728;
  if (j < 288){ ws[BF_OFF+j] = (j<16 ? b1[j] : (j<32 ? b2[j-16] : b3[j-32])); return; }
  j -= 288;
  if (j < 256){ ws[CW1_OFF+j] = cw1[j]; return; }
  j -= 256;
  if (j < 512){ ws[CW2_OFF+j] = cw2[j]; return; }
  j -= 512;
  if (j < 32){ ws[CW2B_OFF+j] = cw2b[j]; return; }
  j -= 32;
  if (j < 64){
    int set = j >> 4, c = j & 15;
    float o;
    if (set == 0){ o = g1[c] * rsqrtf(v1[c] + 1e-5f); }
    else if (set == 1){ float s = g1[c] * rsqrtf(v1[c] + 1e-5f); o = be1[c] - m1[c]*s; }
    else if (set == 2){ o = g2[c] * rsqrtf(v2[c] + 1e-5f); }
    else { float s = g2[c] * rsqrtf(v2[c] + 1e-5f); o = be2[c] - m2[c]*s; }
    ws[BNC_OFF+j] = o;
    return;
  }
  j -= 64;
  if (j < 14592){                          // P2t[i][g*8+o] = p2[(g*8+o)*57 + i]
    int i = j >> 8, rem = j & 255;
    ws[P2T_OFF + j] = p2[rem*57 + i];
    return;
  }
}

// ===================== K1: projection (q,k,v) =====================
// 196 pixel-chunks (4 imgs x 49 chunks of 64 px) x 9 oc-groups = 1764 waves = 441 blocks
__global__ __launch_bounds__(256,2) void k1_proj(const float* __restrict__ x,
                                                 float* __restrict__ ws,
                                                 ushort_t* __restrict__ x3b)
{
  int wid = blockIdx.x*4 + (threadIdx.x>>6);
  int lane = threadIdx.x & 63;
  int chunk = wid / 9, pair = wid - chunk*9;     // chunk in [0,196), pair in [0,9)
  int b = chunk / 49, pp = (chunk - b*49) * 64;
  int oc0 = pair * 32;
  const float* Wt = ws + WT_OFF;
  float acc[32];
  #pragma unroll
  for (int j=0;j<32;j++) acc[j] = ws[BF_OFF + oc0 + j];
  const float* xp = x + ((size_t)b*CIN)*NPIX + pp + lane;
  #pragma unroll 4
  for (int c=0;c<CIN;c++){
    float xv = xp[(size_t)c*NPIX];
    #pragma unroll
    for (int j=0;j<32;j++) acc[j] += xv * Wt[c*288 + oc0 + j];
  }
  int sp = pp + lane;
  if (oc0 == 0){
    #pragma unroll
    for (int j=0;j<16;j++) ws[X1_OFF + (b*16+j)*NPIX + sp] = acc[j];
    #pragma unroll
    for (int j=0;j<16;j++) ws[X2_OFF + (b*16+j)*NPIX + sp] = acc[16+j];
  } else {
    // x3b layout: [b][pix][c]  (bf16 staging of the value projection)
    #pragma unroll
    for (int j=0;j<32;j++){
      int oc = oc0 - 32 + j;
      x3b[((size_t)b*NPIX + sp)*256 + oc] = f2b(acc[j]);
    }
  }
}

// ===================== K2: simple transliterated attention =====================
// one block per (b, pixel); 256 threads; no shuffles / vector casts / fast-rcp
__global__ __launch_bounds__(256) void k2_simple(const float* __restrict__ ws,
                                                 const ushort_t* __restrict__ x3b,
                                                 float* __restrict__ out)
{
  __shared__ float lg_s[49*32];
  __shared__ float w_s[49*32];
  __shared__ float aggv[256];

  int tid = threadIdx.x;
  int bid = blockIdx.x;            // = b*3136 + pix
  int b = bid / NPIX, pix = bid - b*NPIX;
  int y = pix / HW, x = pix - y*HW;

  const float* bnc  = ws + BNC_OFF;
  const float* cw1  = ws + CW1_OFF;
  const float* cw2  = ws + CW2_OFF;
  const float* cw2b = ws + CW2B_OFF;

  // ---- phase 1: per-tap MLP -> logits[tap][g] ----
  if (tid < 49){
    int ki = tid / 7, kj = tid - ki*7;
    int gy = refl(y + ki - 3), gx = refl(x + kj - 3);
    int go = gy*HW + gx;
    float h1[16], t[16];
    #pragma unroll
    for (int c=0;c<16;c++){
      float q  = ws[X1_OFF + (b*16+c)*NPIX + pix];
      float kv = ws[X2_OFF + (b*16+c)*NPIX + go];
      float d = q - kv;
      h1[c] = fmaxf(d*bnc[c] + bnc[16+c], 0.f);
    }
    #pragma unroll
    for (int o=0;o<16;o++){
      float a = 0.f;
      #pragma unroll
      for (int c=0;c<16;c++) a += cw1[o*16+c]*h1[c];
      t[o] = fmaxf(a*bnc[32+o] + bnc[48+o], 0.f);
    }
    for (int g=0;g<32;g++){
      float a = cw2b[g];
      #pragma unroll
      for (int o=0;o<16;o++) a += cw2[g*16+o]*t[o];
      lg_s[tid*32 + g] = a;
    }
  }
  __syncthreads();

  // ---- phase 2: serial softmax over 49 taps, per g ----
  if (tid < 32){
    int g = tid;
    float m = -3.0e38f;
    for (int k=0;k<49;k++) m = fmaxf(m, lg_s[k*32+g]);
    float s = 0.f;
    for (int k=0;k<49;k++){ float e = __expf(lg_s[k*32+g]-m); w_s[k*32+g] = e; s += e; }
    float inv = 1.f / s;
    for (int k=0;k<49;k++) w_s[k*32+g] *= inv;
  }
  __syncthreads();

  // ---- phase 3: aggregation, thread = channel c ----
  {
    int c = tid;
    int g = c >> 3;
    const ushort_t* xb = x3b + (size_t)b*NPIX*256 + c;
    float a = 0.f;
    for (int k=0;k<49;k++){
      int ki = k/7, kj = k - ki*7;
      int gy = refl(y + ki - 3), gx = refl(x + kj - 3);
      a += w_s[k*32+g] * b2f(xb[(size_t)(gy*HW+gx)*256]);
    }
    aggv[c] = a;
  }
  __syncthreads();

  // ---- phase 4: position2, thread = out channel c ----
  {
    int c = tid, g = c >> 3;
    const float* P2 = ws + P2T_OFF;
    float r = 0.f;
    #pragma unroll
    for (int i=0;i<8;i++) r += aggv[i*32+g] * P2[i*256 + c];
    for (int k=0;k<49;k++) r += w_s[k*32+g] * P2[(8+k)*256 + c];
    out[((size_t)b*256 + c)*NPIX + pix] = r;
  }
}

// ===================== launch =====================
extern "C" void kernel_launch(void* const* d_in, const int* in_sizes, int n_in,
                              void* d_out, int out_size, void* d_ws, size_t ws_size,
                              hipStream_t stream) {
  const float* x    = (const float*)d_in[0];
  const float* w1   = (const float*)d_in[1];
  const float* b1   = (const float*)d_in[2];
  const float* w2   = (const float*)d_in[3];
  const float* b2   = (const float*)d_in[4];
  const float* w3   = (const float*)d_in[5];
  const float* b3   = (const float*)d_in[6];
  const float* g1   = (const float*)d_in[7];
  const float* be1  = (const float*)d_in[8];
  const float* m1   = (const float*)d_in[9];
  const float* v1   = (const float*)d_in[10];
  const float* cw1  = (const float*)d_in[11];
  const float* g2   = (const float*)d_in[12];
  const float* be2  = (const float*)d_in[13];
  const float* m2   = (const float*)d_in[14];
  const float* v2   = (const float*)d_in[15];
  const float* cw2  = (const float*)d_in[16];
  const float* cw2b = (const float*)d_in[17];
  const float* p2   = (const float*)d_in[18];

  float* wsf = (float*)d_ws;
  ushort_t* x3b = (ushort_t*)((char*)d_ws + X3_BYTE_OFF);
  float* o = (float*)d_out;

  k0_prep<<<350, 256, 0, stream>>>(w1,b1,w2,b2,w3,b3,g1,be1,m1,v1,cw1,g2,be2,m2,v2,cw2,cw2b,p2,wsf);
  k1_proj<<<441, 256, 0, stream>>>(x, wsf, x3b);
  k2_simple<<<12544, 256, 0, stream>>>(wsf, x3b, o);
}

// Round 5
// 109.065 us; speedup vs baseline: 4.0348x; 4.0348x over previous
//
#include <hip/hip_runtime.h>

#define HW 56
#define NPIX 3136          // 56*56
#define CIN 256
#define OUTC 256

typedef unsigned short ushort_t;
typedef unsigned int uint_t;

__device__ __forceinline__ float b2f(ushort_t u){ return __uint_as_float(((uint_t)u)<<16); }
__device__ __forceinline__ float blo(uint_t u){ return __uint_as_float(u<<16); }
__device__ __forceinline__ float bhi(uint_t u){ return __uint_as_float(u & 0xffff0000u); }
__device__ __forceinline__ ushort_t f2b(float f){
  uint_t u = __float_as_uint(f);
  u += 0x7fffu + ((u>>16)&1u);
  return (ushort_t)(u>>16);
}
__device__ __forceinline__ int refl(int v){ v = v<0 ? -v : v; return v>=HW ? 2*HW-2-v : v; }

// ---- workspace layout (float element offsets unless noted) ----
#define WT_OFF   0          // Wt[256][288] fp32 (transposed proj weights, rows=cin)
#define BF_OFF   73728      // bias[288] (pad to 320)
#define CW1_OFF  74048      // cw1[16][16]
#define CW2_OFF  74304      // cw2[32][16]
#define CW2B_OFF 74816      // cw2b[32] (pad 64)
#define BNC_OFF  74880      // bn1s[16] bn1b[16] bn2s[16] bn2b[16]
#define P2T_OFF  74944      // P2t[57][256] = 14592, P2t[i][g*8+o] = p2[g][o][i]
#define X1T_OFF  89600      // x1t[4][3136][16] fp32 (pixel-major)
#define X2T_OFF  290304     // x2t[4][3136][16] fp32 (pixel-major)
#define X3_BYTE_OFF 1964032 // x3b[4][3136][256] bf16 (6,422,528 B) -> total ws = 8,386,560 B

// ===================== K0: weight prep (fp32 inputs) =====================
__global__ void k0_prep(const float* __restrict__ w1, const float* __restrict__ b1,
                        const float* __restrict__ w2, const float* __restrict__ b2,
                        const float* __restrict__ w3, const float* __restrict__ b3,
                        const float* __restrict__ g1, const float* __restrict__ be1,
                        const float* __restrict__ m1, const float* __restrict__ v1,
                        const float* __restrict__ cw1,
                        const float* __restrict__ g2, const float* __restrict__ be2,
                        const float* __restrict__ m2, const float* __restrict__ v2,
                        const float* __restrict__ cw2, const float* __restrict__ cw2b,
                        const float* __restrict__ p2,
                        float* __restrict__ ws)
{
  int idx = blockIdx.x*256 + threadIdx.x;
  if (idx < 73728){                       // Wt[c][r] = W[r][c]
    int c = idx / 288, r = idx - c*288;
    float v;
    if (r < 16)      v = w1[r*256 + c];
    else if (r < 32) v = w2[(r-16)*256 + c];
    else             v = w3[(r-32)*256 + c];
    ws[WT_OFF + idx] = v;
    return;
  }
  int j = idx - 73728;
  if (j < 288){ ws[BF_OFF+j] = (j<16 ? b1[j] : (j<32 ? b2[j-16] : b3[j-32])); return; }
  j -= 288;
  if (j < 256){ ws[CW1_OFF+j] = cw1[j]; return; }
  j -= 256;
  if (j < 512){ ws[CW2_OFF+j] = cw2[j]; return; }
  j -= 512;
  if (j < 32){ ws[CW2B_OFF+j] = cw2b[j]; return; }
  j -= 32;
  if (j < 64){
    int set = j >> 4, c = j & 15;
    float o;
    if (set == 0){ o = g1[c] * rsqrtf(v1[c] + 1e-5f); }
    else if (set == 1){ float s = g1[c] * rsqrtf(v1[c] + 1e-5f); o = be1[c] - m1[c]*s; }
    else if (set == 2){ o = g2[c] * rsqrtf(v2[c] + 1e-5f); }
    else { float s = g2[c] * rsqrtf(v2[c] + 1e-5f); o = be2[c] - m2[c]*s; }
    ws[BNC_OFF+j] = o;
    return;
  }
  j -= 64;
  if (j < 14592){                          // P2t[i][g*8+o] = p2[(g*8+o)*57 + i]
    int i = j >> 8, rem = j & 255;
    ws[P2T_OFF + j] = p2[rem*57 + i];
    return;
  }
}

// ===================== K1: projection (q,k,v) =====================
// 196 pixel-chunks (4 imgs x 49 chunks of 64 px) x 9 oc-groups = 1764 waves = 441 blocks
__global__ __launch_bounds__(256,2) void k1_proj(const float* __restrict__ x,
                                                 float* __restrict__ ws,
                                                 ushort_t* __restrict__ x3b)
{
  int wid = __builtin_amdgcn_readfirstlane(blockIdx.x*4 + (threadIdx.x>>6));
  int lane = threadIdx.x & 63;
  int chunk = wid / 9, pair = wid - chunk*9;     // chunk in [0,196), pair in [0,9)
  int b = chunk / 49, pp = (chunk - b*49) * 64;
  int oc0 = pair * 32;
  const float* Wt = ws + WT_OFF;
  float acc[32];
  #pragma unroll
  for (int j=0;j<32;j++) acc[j] = ws[BF_OFF + oc0 + j];
  const float* xp = x + ((size_t)b*CIN)*NPIX + pp + lane;
  #pragma unroll 4
  for (int c=0;c<CIN;c++){
    float xv = xp[(size_t)c*NPIX];
    #pragma unroll
    for (int j=0;j<32;j++) acc[j] += xv * Wt[c*288 + oc0 + j];   // uniform -> s_load
  }
  int sp = pp + lane;
  if (oc0 == 0){
    float4* x1o = (float4*)(ws + X1T_OFF + (size_t)(b*NPIX+sp)*16);
    x1o[0] = make_float4(acc[0],acc[1],acc[2],acc[3]);
    x1o[1] = make_float4(acc[4],acc[5],acc[6],acc[7]);
    x1o[2] = make_float4(acc[8],acc[9],acc[10],acc[11]);
    x1o[3] = make_float4(acc[12],acc[13],acc[14],acc[15]);
    float4* x2o = (float4*)(ws + X2T_OFF + (size_t)(b*NPIX+sp)*16);
    x2o[0] = make_float4(acc[16],acc[17],acc[18],acc[19]);
    x2o[1] = make_float4(acc[20],acc[21],acc[22],acc[23]);
    x2o[2] = make_float4(acc[24],acc[25],acc[26],acc[27]);
    x2o[3] = make_float4(acc[28],acc[29],acc[30],acc[31]);
  } else {
    // x3b layout: [b][pix][c]  (bf16 staging of the value projection)
    #pragma unroll
    for (int j=0;j<32;j++){
      int oc = oc0 - 32 + j;
      x3b[((size_t)b*NPIX + sp)*256 + oc] = f2b(acc[j]);
    }
  }
}

// ===================== K2: fused attention, wave-per-pixel =====================
// block = 4 waves = 4 consecutive x-pixels (same row); no x2/x3 LDS staging (L2-hot)
#define WST 33              // w_s row stride (floats)
__global__ __launch_bounds__(256,4) void k2_fused(const float* __restrict__ ws,
                                                  const ushort_t* __restrict__ x3b,
                                                  float* __restrict__ out)
{
  __shared__ float w_s[4*49*WST + 4];   // per-wave [49][32] (stride 33), unnormalized exp
  __shared__ __align__(16) float ags[4*256];
  __shared__ float invs[4*32];

  int tid = threadIdx.x;
  int bid = blockIdx.x;                 // 3136 blocks: b*784 + row*14 + xs4
  int b = bid / 784; int rem = bid - b*784;
  int row = rem / 14, xs4 = rem - row*14;
  int wv = __builtin_amdgcn_readfirstlane(tid >> 6);
  int lane = tid & 63;
  int y = row, x = xs4*4 + wv;
  int pix = y*HW + x;

  const float* bnc  = ws + BNC_OFF;
  const float* cw1  = ws + CW1_OFF;
  const float* cw2  = ws + CW2_OFF;
  const float* cw2b = ws + CW2B_OFF;
  float* wp = w_s + wv*49*WST;

  // ---- phase 1: per-tap MLP (lane = tap) ----
  {
    int k = lane;
    int kk = k < 49 ? k : 48;
    int ki = kk / 7, kj = kk - ki*7;
    int gy = refl(y + ki - 3), gx = refl(x + kj - 3);
    int go = gy*HW + gx;

    const float*  x1p = ws + X1T_OFF + (size_t)(b*NPIX + pix)*16;   // uniform -> s_load
    const float4* x2p = (const float4*)(ws + X2T_OFF + (size_t)(b*NPIX + go)*16);
    float4 v0 = x2p[0], v1 = x2p[1], v2 = x2p[2], v3 = x2p[3];
    float x2v[16] = {v0.x,v0.y,v0.z,v0.w, v1.x,v1.y,v1.z,v1.w,
                     v2.x,v2.y,v2.z,v2.w, v3.x,v3.y,v3.z,v3.w};
    float h1[16], t[16];
    #pragma unroll
    for (int c=0;c<16;c++){
      float d = x1p[c] - x2v[c];
      h1[c] = fmaxf(d*bnc[c] + bnc[16+c], 0.f);
    }
    #pragma unroll
    for (int o=0;o<16;o++){
      float a = 0.f;
      #pragma unroll
      for (int c=0;c<16;c++) a += cw1[o*16+c]*h1[c];
      t[o] = fmaxf(a*bnc[32+o] + bnc[48+o], 0.f);
    }
    if (k < 49){
      #pragma unroll
      for (int g=0;g<32;g++){
        float a = cw2b[g];
        #pragma unroll
        for (int o=0;o<16;o++) a += cw2[g*16+o]*t[o];
        wp[k*WST + g] = a;
      }
    }
  }

  // ---- phase 2: softmax over 49 taps, half-wave split (lane = half*32+g) ----
  {
    int half = lane >> 5, g = lane & 31;
    float M = -3.0e38f;
    #pragma unroll
    for (int i=0;i<25;i++){
      if (half == 0 || i < 24){
        int k = half*25 + i;
        M = fmaxf(M, wp[k*WST + g]);
      }
    }
    M = fmaxf(M, __shfl_xor(M, 32, 64));
    float s = 0.f;
    #pragma unroll
    for (int i=0;i<25;i++){
      if (half == 0 || i < 24){
        int k = half*25 + i;
        float e = __expf(wp[k*WST + g] - M);
        wp[k*WST + g] = e;
        s += e;
      }
    }
    s += __shfl_xor(s, 32, 64);
    if (half == 0) invs[wv*32 + g] = 1.f / s;
  }

  // ---- phase 3: aggregation (lane owns channels 4L..4L+3, single g) ----
  {
    int g_ = lane >> 1;
    int c0 = lane * 4;
    float inv = invs[wv*32 + g_];
    float a0=0.f,a1=0.f,a2=0.f,a3=0.f;
    const ushort_t* xb = x3b + (size_t)b*NPIX*256 + c0;
    #pragma unroll
    for (int kt=0;kt<49;kt++){
      int ii = kt/7, jj = kt - ii*7;
      int gy = refl(y + ii - 3), gx = refl(x + jj - 3);
      int gp = gy*HW + gx;                          // wave-uniform
      float wgt = wp[kt*WST + g_];
      uint2 d = *(const uint2*)(xb + (size_t)gp*256);
      a0 += wgt * blo(d.x);
      a1 += wgt * bhi(d.x);
      a2 += wgt * blo(d.y);
      a3 += wgt * bhi(d.y);
    }
    *(float4*)&ags[wv*256 + c0] = make_float4(a0*inv, a1*inv, a2*inv, a3*inv);
  }
  __syncthreads();

  // ---- phase 4: position2, block-wide (thread = out channel c, 4 px) ----
  {
    int c = tid, g4 = c >> 3;
    const float* P2 = ws + P2T_OFF;
    float i0 = invs[0*32+g4], i1 = invs[1*32+g4], i2 = invs[2*32+g4], i3 = invs[3*32+g4];
    float r0=0.f, r1=0.f, r2=0.f, r3=0.f;
    #pragma unroll
    for (int i=0;i<8;i++){
      float pv = P2[i*256 + c];
      r0 += ags[0*256 + i*32 + g4] * pv;
      r1 += ags[1*256 + i*32 + g4] * pv;
      r2 += ags[2*256 + i*32 + g4] * pv;
      r3 += ags[3*256 + i*32 + g4] * pv;
    }
    #pragma unroll 7
    for (int kt=0;kt<49;kt++){
      float pv = P2[(8+kt)*256 + c];
      r0 += w_s[0*49*WST + kt*WST + g4] * i0 * pv;
      r1 += w_s[1*49*WST + kt*WST + g4] * i1 * pv;
      r2 += w_s[2*49*WST + kt*WST + g4] * i2 * pv;
      r3 += w_s[3*49*WST + kt*WST + g4] * i3 * pv;
    }
    int pix0 = y*HW + xs4*4;
    *(float4*)(out + ((size_t)(b*256 + c))*NPIX + pix0) = make_float4(r0,r1,r2,r3);
  }
}

// ===================== launch =====================
extern "C" void kernel_launch(void* const* d_in, const int* in_sizes, int n_in,
                              void* d_out, int out_size, void* d_ws, size_t ws_size,
                              hipStream_t stream) {
  const float* x    = (const float*)d_in[0];
  const float* w1   = (const float*)d_in[1];
  const float* b1   = (const float*)d_in[2];
  const float* w2   = (const float*)d_in[3];
  const float* b2   = (const float*)d_in[4];
  const float* w3   = (const float*)d_in[5];
  const float* b3   = (const float*)d_in[6];
  const float* g1   = (const float*)d_in[7];
  const float* be1  = (const float*)d_in[8];
  const float* m1   = (const float*)d_in[9];
  const float* v1   = (const float*)d_in[10];
  const float* cw1  = (const float*)d_in[11];
  const float* g2   = (const float*)d_in[12];
  const float* be2  = (const float*)d_in[13];
  const float* m2   = (const float*)d_in[14];
  const float* v2   = (const float*)d_in[15];
  const float* cw2  = (const float*)d_in[16];
  const float* cw2b = (const float*)d_in[17];
  const float* p2   = (const float*)d_in[18];

  float* wsf = (float*)d_ws;
  ushort_t* x3b = (ushort_t*)((char*)d_ws + X3_BYTE_OFF);
  float* o = (float*)d_out;

  k0_prep<<<350, 256, 0, stream>>>(w1,b1,w2,b2,w3,b3,g1,be1,m1,v1,cw1,g2,be2,m2,v2,cw2,cw2b,p2,wsf);
  k1_proj<<<441, 256, 0, stream>>>(x, wsf, x3b);
  k2_fused<<<3136, 256, 0, stream>>>(wsf, x3b, o);
}